// Round 5
// baseline (483.215 us; speedup 1.0000x reference)
//
#include <hip/hip_runtime.h>
#include <hip/hip_bf16.h>

#define Bn 128
#define Tn 512
#define En 100
#define G4 256   // 4*HD
#define Hn 128
#define Kn 12

// Raw barrier: lgkmcnt(0) ensures in-flight LDS ops landed (cross-wave WAR
// safety), s_barrier without the compiler's vmcnt(0) drain so global
// prefetch loads stay in flight across it.
__device__ __forceinline__ void wg_barrier() {
  asm volatile("s_waitcnt lgkmcnt(0)" ::: "memory");
  __builtin_amdgcn_s_barrier();
  asm volatile("" ::: "memory");
}

__device__ __forceinline__ float exp2_hw(float x) {
  float r; asm("v_exp_f32 %0, %1" : "=v"(r) : "v"(x)); return r;
}
__device__ __forceinline__ float rcp_hw(float x) {
  float r; asm("v_rcp_f32 %0, %1" : "=v"(r) : "v"(x)); return r;
}
__device__ __forceinline__ float fast_sigm(float x) {
  return rcp_hw(1.0f + exp2_hw(x * -1.4426950408889634f));
}
__device__ __forceinline__ float fast_tanh(float x) {
  return 1.0f - 2.0f * rcp_hw(1.0f + exp2_hw(x * 2.8853900817779268f));
}

// ---------------- K1: embedding gather + input projection ----------------
__global__ __launch_bounds__(256) void proj_kernel(
    const int* __restrict__ sent, const float* __restrict__ embed,
    const float* __restrict__ Wih, const float* __restrict__ bih,
    const float* __restrict__ bhh, float* __restrict__ xg) {
  __shared__ __align__(16) float embT[En * 64];  // [e][r]
  __shared__ __align__(16) float Wt[En * 64];    // [e][g_local]
  __shared__ __align__(16) float bias_s[64];
  const int tid = threadIdx.x;
  const int n0 = blockIdx.x * 64;
  const int r = tid >> 2;
  const int eo = (tid & 3) * 25;
  {
    const int row = sent[n0 + r];
    const float* erow = embed + (size_t)row * En;
#pragma unroll
    for (int i = 0; i < 25; ++i) embT[(eo + i) * 64 + r] = erow[eo + i];
  }
  const int rg = tid & 15;
  const int gg = tid >> 4;
  for (int ch = 0; ch < 4; ++ch) {
    {
      const float* wrow = Wih + (size_t)(ch * 64 + r) * En;
#pragma unroll
      for (int i = 0; i < 25; ++i) Wt[(eo + i) * 64 + r] = wrow[eo + i];
      if (tid < 64) bias_s[tid] = bih[ch * 64 + tid] + bhh[ch * 64 + tid];
    }
    __syncthreads();
    float acc[4][4];
    {
      const float4 bv = *(const float4*)&bias_s[4 * gg];
#pragma unroll
      for (int i = 0; i < 4; ++i) {
        acc[i][0] = bv.x; acc[i][1] = bv.y; acc[i][2] = bv.z; acc[i][3] = bv.w;
      }
    }
#pragma unroll 4
    for (int e = 0; e < En; ++e) {
      const float4 a = *(const float4*)&embT[e * 64 + 4 * rg];
      const float4 w = *(const float4*)&Wt[e * 64 + 4 * gg];
      acc[0][0] = fmaf(a.x, w.x, acc[0][0]); acc[0][1] = fmaf(a.x, w.y, acc[0][1]);
      acc[0][2] = fmaf(a.x, w.z, acc[0][2]); acc[0][3] = fmaf(a.x, w.w, acc[0][3]);
      acc[1][0] = fmaf(a.y, w.x, acc[1][0]); acc[1][1] = fmaf(a.y, w.y, acc[1][1]);
      acc[1][2] = fmaf(a.y, w.z, acc[1][2]); acc[1][3] = fmaf(a.y, w.w, acc[1][3]);
      acc[2][0] = fmaf(a.z, w.x, acc[2][0]); acc[2][1] = fmaf(a.z, w.y, acc[2][1]);
      acc[2][2] = fmaf(a.z, w.z, acc[2][2]); acc[2][3] = fmaf(a.z, w.w, acc[2][3]);
      acc[3][0] = fmaf(a.w, w.x, acc[3][0]); acc[3][1] = fmaf(a.w, w.y, acc[3][1]);
      acc[3][2] = fmaf(a.w, w.z, acc[3][2]); acc[3][3] = fmaf(a.w, w.w, acc[3][3]);
    }
#pragma unroll
    for (int i = 0; i < 4; ++i) {
      *(float4*)&xg[(size_t)(n0 + 4 * rg + i) * G4 + ch * 64 + 4 * gg] =
          make_float4(acc[i][0], acc[i][1], acc[i][2], acc[i][3]);
    }
    __syncthreads();
  }
}

// ---------------- K2: LSTM recurrence (K-split, 8 waves/pair) ----------------
// One block (512 threads) per (dir,b) pair. Thread = (gate g = tid>>1,
// half = tid&1): 32-long half-dot, halves combined with shfl_xor(1).
// W_hh half-row lives in 8 NAMED float4s (rule #20: an array + asm-opacity
// loop got scratch-demoted in round 4; named SSA values with per-value
// opacity cannot be). Opacity stops the allocator from sinking the
// loop-invariant weight loads back into the 512-step loop (round-3 failure).
__global__ __launch_bounds__(512, 2) void lstm_kernel(
    const float* __restrict__ xgF, const float* __restrict__ xgB,
    const float* __restrict__ WhhF, const float* __restrict__ WhhB,
    const float* __restrict__ h0, const float* __restrict__ c0,
    float* __restrict__ feats, int dirSel) {
  __shared__ __align__(16) float h_lds[8][64];     // per-wave private copies
  __shared__ __align__(16) float gates_s[2][256];  // [buf][g], g = type*64+unit
  int d, b;
  if (dirSel < 0) { d = blockIdx.x >> 7; b = blockIdx.x & 127; }
  else            { d = dirSel;          b = blockIdx.x; }
  const int tid = threadIdx.x;
  const int g = tid >> 1;        // gate row 0..255
  const int half = tid & 1;      // K half
  const int l = tid & 63;        // lane
  const int w = tid >> 6;        // wave 0..7
  const int w_u = __builtin_amdgcn_readfirstlane(w);
  const int isTanhW = (w_u >> 1) == 2;   // gate type g>>6 == 2 (PyTorch i,f,g,o)
  const float* xg = d ? xgB : xgF;
  const float* Whh = d ? WhhB : WhhF;
  float4 w0, w1, w2, w3, w4, w5, w6, w7;
  {
    const float4* wp = (const float4*)(Whh + (size_t)g * 64 + 32 * half);
    w0 = wp[0]; w1 = wp[1]; w2 = wp[2]; w3 = wp[3];
    w4 = wp[4]; w5 = wp[5]; w6 = wp[6]; w7 = wp[7];
  }
#define OPQ4(v) asm volatile("" : "+v"(v.x), "+v"(v.y), "+v"(v.z), "+v"(v.w))
  OPQ4(w0); OPQ4(w1); OPQ4(w2); OPQ4(w3);
  OPQ4(w4); OPQ4(w5); OPQ4(w6); OPQ4(w7);
#undef OPQ4
  float c = c0[(size_t)d * (Bn * 64) + (size_t)b * 64 + l];
  h_lds[w][l] = h0[(size_t)d * (Bn * 64) + (size_t)b * 64 + l];
  const float* xb = xg + (size_t)b * Tn * G4 + g;
  float* fbase = feats + (size_t)b * Tn * Hn + d * 64 + l;  // wave 0 stores
  const int t0 = d ? (Tn - 1) : 0;
  const int ts = d ? -1 : 1;
  float p0 = 0.f, p1 = 0.f, p2 = 0.f, p3 = 0.f;
  if (half == 0) {
    p0 = xb[(size_t)t0 * G4];
    p1 = xb[(size_t)(t0 + ts) * G4];
    p2 = xb[(size_t)(t0 + 2 * ts) * G4];
    p3 = xb[(size_t)(t0 + 3 * ts) * G4];
  }

#define FMA4(HV, WV)                                                           \
    s0 = fmaf((HV).x, (WV).x, s0); s1 = fmaf((HV).y, (WV).y, s1);              \
    s2 = fmaf((HV).z, (WV).z, s2); s3 = fmaf((HV).w, (WV).w, s3);

#define LSTM_STEP(P, TT, PAR) do {                                             \
    float s0 = 0.f, s1 = 0.f, s2 = 0.f, s3 = 0.f;                              \
    const float4* hp = (const float4*)(&h_lds[w][32 * half]);                  \
    const float4 h0v = hp[0], h1v = hp[1], h2v = hp[2], h3v = hp[3];           \
    const float4 h4v = hp[4], h5v = hp[5], h6v = hp[6], h7v = hp[7];           \
    FMA4(h0v, w0) FMA4(h1v, w1) FMA4(h2v, w2) FMA4(h3v, w3)                    \
    FMA4(h4v, w4) FMA4(h5v, w5) FMA4(h6v, w6) FMA4(h7v, w7)                    \
    const float smine = (s0 + s1) + (s2 + s3);                                 \
    const float stot = smine + __shfl_xor(smine, 1);                           \
    if (half == 0) {                                                           \
      const float accv = (P) + stot;                                           \
      const float act = isTanhW ? fast_tanh(accv) : fast_sigm(accv);           \
      gates_s[PAR][g] = act;                                                   \
    }                                                                          \
    wg_barrier();                                                              \
    const float g0 = gates_s[PAR][l];                                          \
    const float g1 = gates_s[PAR][64 + l];                                     \
    const float g2 = gates_s[PAR][128 + l];                                    \
    const float g3 = gates_s[PAR][192 + l];                                    \
    c = fmaf(g1, c, g0 * g2);                                                  \
    const float hh = g3 * fast_tanh(c);                                        \
    h_lds[w][l] = hh;                                                          \
    if (w_u == 0) fbase[(size_t)(TT) * Hn] = hh;                               \
  } while (0)

  for (int s = 0; s < Tn; s += 4) {
    const int tA = t0 + s * ts;
    LSTM_STEP(p0, tA, 0);
    if (half == 0 && s + 4 < Tn) p0 = xb[(size_t)(t0 + (s + 4) * ts) * G4];
    LSTM_STEP(p1, tA + ts, 1);
    if (half == 0 && s + 5 < Tn) p1 = xb[(size_t)(t0 + (s + 5) * ts) * G4];
    LSTM_STEP(p2, tA + 2 * ts, 0);
    if (half == 0 && s + 6 < Tn) p2 = xb[(size_t)(t0 + (s + 6) * ts) * G4];
    LSTM_STEP(p3, tA + 3 * ts, 1);
    if (half == 0 && s + 7 < Tn) p3 = xb[(size_t)(t0 + (s + 7) * ts) * G4];
  }
#undef LSTM_STEP
#undef FMA4
}

// ---------------- K3: emissions = feats @ W_out^T + b_out ----------------
__global__ __launch_bounds__(256) void emis_kernel(
    const float* __restrict__ feats, const float* __restrict__ Wout,
    const float* __restrict__ bout, float* __restrict__ em) {
  __shared__ __align__(16) float Wo[Kn * Hn];
  __shared__ float bo[Kn];
  const int tid = threadIdx.x;
  for (int i = tid; i < Kn * Hn; i += 256) Wo[i] = Wout[i];
  if (tid < Kn) bo[tid] = bout[tid];
  __syncthreads();
  const int n = blockIdx.x * 256 + tid;
  float acc[Kn];
#pragma unroll
  for (int k = 0; k < Kn; ++k) acc[k] = bo[k];
  const float4* fp = (const float4*)(feats + (size_t)n * Hn);
#pragma unroll 4
  for (int d4 = 0; d4 < 32; ++d4) {
    const float4 v = fp[d4];
#pragma unroll
    for (int k = 0; k < Kn; ++k) {
      const float4 w = *(const float4*)&Wo[k * Hn + d4 * 4];
      acc[k] = fmaf(v.x, w.x, acc[k]);
      acc[k] = fmaf(v.y, w.y, acc[k]);
      acc[k] = fmaf(v.z, w.z, acc[k]);
      acc[k] = fmaf(v.w, w.w, acc[k]);
    }
  }
  float* ep = em + (size_t)n * Kn;
#pragma unroll
  for (int k = 0; k < Kn; k += 4)
    *(float4*)&ep[k] = make_float4(acc[k], acc[k + 1], acc[k + 2], acc[k + 3]);
}

// ---------------- K4: Viterbi (one wave per sentence) ----------------
#define AMAX(v, a, v2, a2) { if ((v2) > (v)) { (v) = (v2); (a) = (a2); } }

__global__ __launch_bounds__(64) void viterbi_kernel(
    const float* __restrict__ em, const float* __restrict__ trans,
    float* __restrict__ out) {
  __shared__ __align__(16) float em_s[Tn * Kn];
  __shared__ float trans_s[Kn * Kn];
  __shared__ unsigned char bp[(Tn - 1) * Kn];
  __shared__ short path_s[Tn];
  const int tid = threadIdx.x;
  const int b = blockIdx.x;
  {
    const float4* ebv = (const float4*)(em + (size_t)b * Tn * Kn);
    float4* emv = (float4*)em_s;
    for (int i = tid; i < (Tn * Kn) / 4; i += 64) emv[i] = ebv[i];
  }
  for (int i = tid; i < Kn * Kn; i += 64) trans_s[i] = trans[i];
  __syncthreads();
  const int lane = (tid < Kn) ? tid : 0;  // lane = to-tag
  float treg[Kn];
#pragma unroll
  for (int f = 0; f < Kn; ++f) treg[f] = trans_s[f * Kn + lane];
  float prev = em_s[lane];
  for (int t = 1; t < Tn; ++t) {
    float cv[Kn];
#pragma unroll
    for (int f = 0; f < Kn; ++f) cv[f] = __shfl(prev, f) + treg[f];
    float m0 = cv[0], m1 = cv[2], m2 = cv[4], m3 = cv[6], m4 = cv[8], m5 = cv[10];
    int a0 = 0, a1 = 2, a2 = 4, a3 = 6, a4 = 8, a5 = 10;
    AMAX(m0, a0, cv[1], 1);  AMAX(m1, a1, cv[3], 3);
    AMAX(m2, a2, cv[5], 5);  AMAX(m3, a3, cv[7], 7);
    AMAX(m4, a4, cv[9], 9);  AMAX(m5, a5, cv[11], 11);
    AMAX(m0, a0, m1, a1); AMAX(m2, a2, m3, a3); AMAX(m4, a4, m5, a5);
    AMAX(m0, a0, m2, a2); AMAX(m0, a0, m4, a4);
    prev = em_s[t * Kn + lane] + m0;
    if (tid < Kn) bp[(t - 1) * Kn + tid] = (unsigned char)a0;
  }
  float fv[Kn];
#pragma unroll
  for (int f = 0; f < Kn; ++f) fv[f] = __shfl(prev, f);
  float m0 = fv[0], m1 = fv[2], m2 = fv[4], m3 = fv[6], m4 = fv[8], m5 = fv[10];
  int a0 = 0, a1 = 2, a2 = 4, a3 = 6, a4 = 8, a5 = 10;
  AMAX(m0, a0, fv[1], 1);  AMAX(m1, a1, fv[3], 3);
  AMAX(m2, a2, fv[5], 5);  AMAX(m3, a3, fv[7], 7);
  AMAX(m4, a4, fv[9], 9);  AMAX(m5, a5, fv[11], 11);
  AMAX(m0, a0, m1, a1); AMAX(m2, a2, m3, a3); AMAX(m4, a4, m5, a5);
  AMAX(m0, a0, m2, a2); AMAX(m0, a0, m4, a4);
  __syncthreads();
  if (tid == 0) {
    out[b] = m0;
    int cur = a0;
    for (int i = Tn - 2; i >= 0; --i) {
      path_s[i + 1] = (short)cur;
      cur = bp[i * Kn + cur];
    }
    path_s[0] = (short)cur;
  }
  __syncthreads();
  for (int i = tid; i < Tn; i += 64)
    out[Bn + (size_t)b * Tn + i] = (float)path_s[i];
}

extern "C" void kernel_launch(void* const* d_in, const int* in_sizes, int n_in,
                              void* d_out, int out_size, void* d_ws, size_t ws_size,
                              hipStream_t stream) {
  const int*   sent  = (const int*)d_in[0];
  const float* embed = (const float*)d_in[1];
  const float* Wih_f = (const float*)d_in[2];
  const float* Whh_f = (const float*)d_in[3];
  const float* bih_f = (const float*)d_in[4];
  const float* bhh_f = (const float*)d_in[5];
  const float* Wih_b = (const float*)d_in[6];
  const float* Whh_b = (const float*)d_in[7];
  const float* bih_b = (const float*)d_in[8];
  const float* bhh_b = (const float*)d_in[9];
  const float* Wout  = (const float*)d_in[10];
  const float* bout  = (const float*)d_in[11];
  const float* trans = (const float*)d_in[12];
  const float* h0    = (const float*)d_in[13];
  const float* c0    = (const float*)d_in[14];
  float* out = (float*)d_out;

  char* ws = (char*)d_ws;
  const size_t xgBytes   = (size_t)Bn * Tn * G4 * sizeof(float);  // 64 MiB
  const size_t featBytes = (size_t)Bn * Tn * Hn * sizeof(float);  // 32 MiB
  const size_t emBytes   = (size_t)Bn * Tn * Kn * sizeof(float);  //  3 MiB
  const int projGrid = (Bn * Tn) / 64;  // 1024

  if (ws_size >= 2 * xgBytes + featBytes + emBytes) {
    float* xgF   = (float*)ws;
    float* xgB   = (float*)(ws + xgBytes);
    float* feats = (float*)(ws + 2 * xgBytes);
    float* emis  = (float*)(ws + 2 * xgBytes + featBytes);
    proj_kernel<<<projGrid, 256, 0, stream>>>(sent, embed, Wih_f, bih_f, bhh_f, xgF);
    proj_kernel<<<projGrid, 256, 0, stream>>>(sent, embed, Wih_b, bih_b, bhh_b, xgB);
    lstm_kernel<<<256, 512, 0, stream>>>(xgF, xgB, Whh_f, Whh_b, h0, c0, feats, -1);
    emis_kernel<<<256, 256, 0, stream>>>(feats, Wout, bout, emis);
    viterbi_kernel<<<128, 64, 0, stream>>>(emis, trans, out);
  } else {
    float* xgS   = (float*)ws;
    float* feats = (float*)(ws + xgBytes);
    float* emis  = (float*)(ws + xgBytes + featBytes);
    proj_kernel<<<projGrid, 256, 0, stream>>>(sent, embed, Wih_f, bih_f, bhh_f, xgS);
    lstm_kernel<<<128, 512, 0, stream>>>(xgS, xgS, Whh_f, Whh_f, h0, c0, feats, 0);
    proj_kernel<<<projGrid, 256, 0, stream>>>(sent, embed, Wih_b, bih_b, bhh_b, xgS);
    lstm_kernel<<<128, 512, 0, stream>>>(xgS, xgS, Whh_b, Whh_b, h0, c0, feats, 1);
    emis_kernel<<<256, 256, 0, stream>>>(feats, Wout, bout, emis);
    viterbi_kernel<<<128, 64, 0, stream>>>(emis, trans, out);
  }
}

// Round 6
// 475.618 us; speedup vs baseline: 1.0160x; 1.0160x over previous
//
#include <hip/hip_runtime.h>
#include <hip/hip_bf16.h>

#define Bn 128
#define Tn 512
#define En 100
#define G4 256   // 4*HD
#define Hn 128
#define Kn 12

// Raw barrier: lgkmcnt(0) ensures in-flight LDS ops landed (cross-wave WAR
// safety), s_barrier without the compiler's vmcnt(0) drain so global
// prefetch loads stay in flight across it.
__device__ __forceinline__ void wg_barrier() {
  asm volatile("s_waitcnt lgkmcnt(0)" ::: "memory");
  __builtin_amdgcn_s_barrier();
  asm volatile("" ::: "memory");
}

__device__ __forceinline__ float exp2_hw(float x) {
  float r; asm("v_exp_f32 %0, %1" : "=v"(r) : "v"(x)); return r;
}
__device__ __forceinline__ float rcp_hw(float x) {
  float r; asm("v_rcp_f32 %0, %1" : "=v"(r) : "v"(x)); return r;
}
__device__ __forceinline__ float fast_sigm(float x) {
  return rcp_hw(1.0f + exp2_hw(x * -1.4426950408889634f));
}
__device__ __forceinline__ float fast_tanh(float x) {
  return 1.0f - 2.0f * rcp_hw(1.0f + exp2_hw(x * 2.8853900817779268f));
}

// ---------------- K1: embedding gather + input projection ----------------
__global__ __launch_bounds__(256) void proj_kernel(
    const int* __restrict__ sent, const float* __restrict__ embed,
    const float* __restrict__ Wih, const float* __restrict__ bih,
    const float* __restrict__ bhh, float* __restrict__ xg) {
  __shared__ __align__(16) float embT[En * 64];  // [e][r]
  __shared__ __align__(16) float Wt[En * 64];    // [e][g_local]
  __shared__ __align__(16) float bias_s[64];
  const int tid = threadIdx.x;
  const int n0 = blockIdx.x * 64;
  const int r = tid >> 2;
  const int eo = (tid & 3) * 25;
  {
    const int row = sent[n0 + r];
    const float* erow = embed + (size_t)row * En;
#pragma unroll
    for (int i = 0; i < 25; ++i) embT[(eo + i) * 64 + r] = erow[eo + i];
  }
  const int rg = tid & 15;
  const int gg = tid >> 4;
  for (int ch = 0; ch < 4; ++ch) {
    {
      const float* wrow = Wih + (size_t)(ch * 64 + r) * En;
#pragma unroll
      for (int i = 0; i < 25; ++i) Wt[(eo + i) * 64 + r] = wrow[eo + i];
      if (tid < 64) bias_s[tid] = bih[ch * 64 + tid] + bhh[ch * 64 + tid];
    }
    __syncthreads();
    float acc[4][4];
    {
      const float4 bv = *(const float4*)&bias_s[4 * gg];
#pragma unroll
      for (int i = 0; i < 4; ++i) {
        acc[i][0] = bv.x; acc[i][1] = bv.y; acc[i][2] = bv.z; acc[i][3] = bv.w;
      }
    }
#pragma unroll 4
    for (int e = 0; e < En; ++e) {
      const float4 a = *(const float4*)&embT[e * 64 + 4 * rg];
      const float4 w = *(const float4*)&Wt[e * 64 + 4 * gg];
      acc[0][0] = fmaf(a.x, w.x, acc[0][0]); acc[0][1] = fmaf(a.x, w.y, acc[0][1]);
      acc[0][2] = fmaf(a.x, w.z, acc[0][2]); acc[0][3] = fmaf(a.x, w.w, acc[0][3]);
      acc[1][0] = fmaf(a.y, w.x, acc[1][0]); acc[1][1] = fmaf(a.y, w.y, acc[1][1]);
      acc[1][2] = fmaf(a.y, w.z, acc[1][2]); acc[1][3] = fmaf(a.y, w.w, acc[1][3]);
      acc[2][0] = fmaf(a.z, w.x, acc[2][0]); acc[2][1] = fmaf(a.z, w.y, acc[2][1]);
      acc[2][2] = fmaf(a.z, w.z, acc[2][2]); acc[2][3] = fmaf(a.z, w.w, acc[2][3]);
      acc[3][0] = fmaf(a.w, w.x, acc[3][0]); acc[3][1] = fmaf(a.w, w.y, acc[3][1]);
      acc[3][2] = fmaf(a.w, w.z, acc[3][2]); acc[3][3] = fmaf(a.w, w.w, acc[3][3]);
    }
#pragma unroll
    for (int i = 0; i < 4; ++i) {
      *(float4*)&xg[(size_t)(n0 + 4 * rg + i) * G4 + ch * 64 + 4 * gg] =
          make_float4(acc[i][0], acc[i][1], acc[i][2], acc[i][3]);
    }
    __syncthreads();
  }
}

// ---------------- K2: LSTM recurrence (K-split, AGPR-resident weights) ----
// One block (512 threads) per (dir,b) pair. Thread = (gate g = tid>>1,
// half = tid&1): 32-long half-dot, halves combined with shfl_xor(1).
// The 32 W_hh values per thread are stashed in AGPRs (unified RF, zero AGPR
// pressure in this MFMA-free kernel) because the VGPR allocator provably
// refuses to keep them live across the 512-step loop (r3: remat global
// loads, r4/r5: scratch spill -> ~700 cyc/step of memory wait on every
// barrier-locked wave). v_accvgpr_read is 1 VALU op -- the "load" is now
// 2 cyc instead of a vmcnt stall.
__global__ __launch_bounds__(512, 2) void lstm_kernel(
    const float* __restrict__ xgF, const float* __restrict__ xgB,
    const float* __restrict__ WhhF, const float* __restrict__ WhhB,
    const float* __restrict__ h0, const float* __restrict__ c0,
    float* __restrict__ feats, int dirSel) {
  __shared__ __align__(16) float h_lds[8][64];     // per-wave private copies
  __shared__ __align__(16) float gates_s[2][256];  // [buf][g], g = type*64+unit
  int d, b;
  if (dirSel < 0) { d = blockIdx.x >> 7; b = blockIdx.x & 127; }
  else            { d = dirSel;          b = blockIdx.x; }
  const int tid = threadIdx.x;
  const int g = tid >> 1;        // gate row 0..255
  const int half = tid & 1;      // K half
  const int l = tid & 63;        // lane
  const int w = tid >> 6;        // wave 0..7
  const int w_u = __builtin_amdgcn_readfirstlane(w);
  const int isTanhW = (w_u >> 1) == 2;   // gate type g>>6 == 2 (PyTorch i,f,g,o)
  const float* xg = d ? xgB : xgF;
  const float* Whh = d ? WhhB : WhhF;
  // --- load weights once, stash to AGPRs ---
  float a00,a01,a02,a03,a04,a05,a06,a07,a08,a09,a10,a11,a12,a13,a14,a15,
        a16,a17,a18,a19,a20,a21,a22,a23,a24,a25,a26,a27,a28,a29,a30,a31;
  {
    const float4* wp = (const float4*)(Whh + (size_t)g * 64 + 32 * half);
    const float4 w0 = wp[0], w1 = wp[1], w2 = wp[2], w3 = wp[3];
    const float4 w4 = wp[4], w5 = wp[5], w6 = wp[6], w7 = wp[7];
#define ST(A, V) asm volatile("v_accvgpr_write_b32 %0, %1" : "=a"(A) : "v"(V))
    ST(a00, w0.x); ST(a01, w0.y); ST(a02, w0.z); ST(a03, w0.w);
    ST(a04, w1.x); ST(a05, w1.y); ST(a06, w1.z); ST(a07, w1.w);
    ST(a08, w2.x); ST(a09, w2.y); ST(a10, w2.z); ST(a11, w2.w);
    ST(a12, w3.x); ST(a13, w3.y); ST(a14, w3.z); ST(a15, w3.w);
    ST(a16, w4.x); ST(a17, w4.y); ST(a18, w4.z); ST(a19, w4.w);
    ST(a20, w5.x); ST(a21, w5.y); ST(a22, w5.z); ST(a23, w5.w);
    ST(a24, w6.x); ST(a25, w6.y); ST(a26, w6.z); ST(a27, w6.w);
    ST(a28, w7.x); ST(a29, w7.y); ST(a30, w7.z); ST(a31, w7.w);
#undef ST
  }
  float c = c0[(size_t)d * (Bn * 64) + (size_t)b * 64 + l];
  h_lds[w][l] = h0[(size_t)d * (Bn * 64) + (size_t)b * 64 + l];
  const float* xb = xg + (size_t)b * Tn * G4 + g;
  float* fbase = feats + (size_t)b * Tn * Hn + d * 64 + l;  // wave 0 stores
  const int t0 = d ? (Tn - 1) : 0;
  const int ts = d ? -1 : 1;
  float p0 = 0.f, p1 = 0.f, p2 = 0.f, p3 = 0.f;
  if (half == 0) {
    p0 = xb[(size_t)t0 * G4];
    p1 = xb[(size_t)(t0 + ts) * G4];
    p2 = xb[(size_t)(t0 + 2 * ts) * G4];
    p3 = xb[(size_t)(t0 + 3 * ts) * G4];
  }

// volatile reads: must re-read from AGPR each step so the values never
// become VGPR-live across the loop (which the allocator would spill).
#define DOT4(HV, A0, A1, A2, A3) {                                             \
    float u0, u1, u2, u3;                                                      \
    asm volatile("v_accvgpr_read_b32 %0, %1" : "=v"(u0) : "a"(A0));            \
    asm volatile("v_accvgpr_read_b32 %0, %1" : "=v"(u1) : "a"(A1));            \
    asm volatile("v_accvgpr_read_b32 %0, %1" : "=v"(u2) : "a"(A2));            \
    asm volatile("v_accvgpr_read_b32 %0, %1" : "=v"(u3) : "a"(A3));            \
    s0 = fmaf((HV).x, u0, s0); s1 = fmaf((HV).y, u1, s1);                      \
    s2 = fmaf((HV).z, u2, s2); s3 = fmaf((HV).w, u3, s3); }

#define LSTM_STEP(P, TT, PAR) do {                                             \
    float s0 = 0.f, s1 = 0.f, s2 = 0.f, s3 = 0.f;                              \
    const float4* hp = (const float4*)(&h_lds[w][32 * half]);                  \
    const float4 h0v = hp[0], h1v = hp[1], h2v = hp[2], h3v = hp[3];           \
    const float4 h4v = hp[4], h5v = hp[5], h6v = hp[6], h7v = hp[7];           \
    DOT4(h0v, a00, a01, a02, a03)                                              \
    DOT4(h1v, a04, a05, a06, a07)                                              \
    DOT4(h2v, a08, a09, a10, a11)                                              \
    DOT4(h3v, a12, a13, a14, a15)                                              \
    DOT4(h4v, a16, a17, a18, a19)                                              \
    DOT4(h5v, a20, a21, a22, a23)                                              \
    DOT4(h6v, a24, a25, a26, a27)                                              \
    DOT4(h7v, a28, a29, a30, a31)                                              \
    const float smine = (s0 + s1) + (s2 + s3);                                 \
    const float stot = smine + __shfl_xor(smine, 1);                           \
    if (half == 0) {                                                           \
      const float accv = (P) + stot;                                           \
      const float act = isTanhW ? fast_tanh(accv) : fast_sigm(accv);           \
      gates_s[PAR][g] = act;                                                   \
    }                                                                          \
    wg_barrier();                                                              \
    const float g0 = gates_s[PAR][l];                                          \
    const float g1 = gates_s[PAR][64 + l];                                     \
    const float g2 = gates_s[PAR][128 + l];                                    \
    const float g3 = gates_s[PAR][192 + l];                                    \
    c = fmaf(g1, c, g0 * g2);                                                  \
    const float hh = g3 * fast_tanh(c);                                        \
    h_lds[w][l] = hh;                                                          \
    if (w_u == 0) fbase[(size_t)(TT) * Hn] = hh;                               \
  } while (0)

  for (int s = 0; s < Tn; s += 4) {
    const int tA = t0 + s * ts;
    LSTM_STEP(p0, tA, 0);
    if (half == 0 && s + 4 < Tn) p0 = xb[(size_t)(t0 + (s + 4) * ts) * G4];
    LSTM_STEP(p1, tA + ts, 1);
    if (half == 0 && s + 5 < Tn) p1 = xb[(size_t)(t0 + (s + 5) * ts) * G4];
    LSTM_STEP(p2, tA + 2 * ts, 0);
    if (half == 0 && s + 6 < Tn) p2 = xb[(size_t)(t0 + (s + 6) * ts) * G4];
    LSTM_STEP(p3, tA + 3 * ts, 1);
    if (half == 0 && s + 7 < Tn) p3 = xb[(size_t)(t0 + (s + 7) * ts) * G4];
  }
#undef LSTM_STEP
#undef DOT4
}

// ---------------- K3: emissions = feats @ W_out^T + b_out ----------------
__global__ __launch_bounds__(256) void emis_kernel(
    const float* __restrict__ feats, const float* __restrict__ Wout,
    const float* __restrict__ bout, float* __restrict__ em) {
  __shared__ __align__(16) float Wo[Kn * Hn];
  __shared__ float bo[Kn];
  const int tid = threadIdx.x;
  for (int i = tid; i < Kn * Hn; i += 256) Wo[i] = Wout[i];
  if (tid < Kn) bo[tid] = bout[tid];
  __syncthreads();
  const int n = blockIdx.x * 256 + tid;
  float acc[Kn];
#pragma unroll
  for (int k = 0; k < Kn; ++k) acc[k] = bo[k];
  const float4* fp = (const float4*)(feats + (size_t)n * Hn);
#pragma unroll 4
  for (int d4 = 0; d4 < 32; ++d4) {
    const float4 v = fp[d4];
#pragma unroll
    for (int k = 0; k < Kn; ++k) {
      const float4 w = *(const float4*)&Wo[k * Hn + d4 * 4];
      acc[k] = fmaf(v.x, w.x, acc[k]);
      acc[k] = fmaf(v.y, w.y, acc[k]);
      acc[k] = fmaf(v.z, w.z, acc[k]);
      acc[k] = fmaf(v.w, w.w, acc[k]);
    }
  }
  float* ep = em + (size_t)n * Kn;
#pragma unroll
  for (int k = 0; k < Kn; k += 4)
    *(float4*)&ep[k] = make_float4(acc[k], acc[k + 1], acc[k + 2], acc[k + 3]);
}

// ---------------- K4: Viterbi (one wave per sentence) ----------------
#define AMAX(v, a, v2, a2) { if ((v2) > (v)) { (v) = (v2); (a) = (a2); } }

__global__ __launch_bounds__(64) void viterbi_kernel(
    const float* __restrict__ em, const float* __restrict__ trans,
    float* __restrict__ out) {
  __shared__ __align__(16) float em_s[Tn * Kn];
  __shared__ float trans_s[Kn * Kn];
  __shared__ unsigned char bp[(Tn - 1) * Kn];
  __shared__ short path_s[Tn];
  const int tid = threadIdx.x;
  const int b = blockIdx.x;
  {
    const float4* ebv = (const float4*)(em + (size_t)b * Tn * Kn);
    float4* emv = (float4*)em_s;
    for (int i = tid; i < (Tn * Kn) / 4; i += 64) emv[i] = ebv[i];
  }
  for (int i = tid; i < Kn * Kn; i += 64) trans_s[i] = trans[i];
  __syncthreads();
  const int lane = (tid < Kn) ? tid : 0;  // lane = to-tag
  float treg[Kn];
#pragma unroll
  for (int f = 0; f < Kn; ++f) treg[f] = trans_s[f * Kn + lane];
  float prev = em_s[lane];
  for (int t = 1; t < Tn; ++t) {
    float cv[Kn];
#pragma unroll
    for (int f = 0; f < Kn; ++f) cv[f] = __shfl(prev, f) + treg[f];
    float m0 = cv[0], m1 = cv[2], m2 = cv[4], m3 = cv[6], m4 = cv[8], m5 = cv[10];
    int a0 = 0, a1 = 2, a2 = 4, a3 = 6, a4 = 8, a5 = 10;
    AMAX(m0, a0, cv[1], 1);  AMAX(m1, a1, cv[3], 3);
    AMAX(m2, a2, cv[5], 5);  AMAX(m3, a3, cv[7], 7);
    AMAX(m4, a4, cv[9], 9);  AMAX(m5, a5, cv[11], 11);
    AMAX(m0, a0, m1, a1); AMAX(m2, a2, m3, a3); AMAX(m4, a4, m5, a5);
    AMAX(m0, a0, m2, a2); AMAX(m0, a0, m4, a4);
    prev = em_s[t * Kn + lane] + m0;
    if (tid < Kn) bp[(t - 1) * Kn + tid] = (unsigned char)a0;
  }
  float fv[Kn];
#pragma unroll
  for (int f = 0; f < Kn; ++f) fv[f] = __shfl(prev, f);
  float m0 = fv[0], m1 = fv[2], m2 = fv[4], m3 = fv[6], m4 = fv[8], m5 = fv[10];
  int a0 = 0, a1 = 2, a2 = 4, a3 = 6, a4 = 8, a5 = 10;
  AMAX(m0, a0, fv[1], 1);  AMAX(m1, a1, fv[3], 3);
  AMAX(m2, a2, fv[5], 5);  AMAX(m3, a3, fv[7], 7);
  AMAX(m4, a4, fv[9], 9);  AMAX(m5, a5, fv[11], 11);
  AMAX(m0, a0, m1, a1); AMAX(m2, a2, m3, a3); AMAX(m4, a4, m5, a5);
  AMAX(m0, a0, m2, a2); AMAX(m0, a0, m4, a4);
  __syncthreads();
  if (tid == 0) {
    out[b] = m0;
    int cur = a0;
    for (int i = Tn - 2; i >= 0; --i) {
      path_s[i + 1] = (short)cur;
      cur = bp[i * Kn + cur];
    }
    path_s[0] = (short)cur;
  }
  __syncthreads();
  for (int i = tid; i < Tn; i += 64)
    out[Bn + (size_t)b * Tn + i] = (float)path_s[i];
}

extern "C" void kernel_launch(void* const* d_in, const int* in_sizes, int n_in,
                              void* d_out, int out_size, void* d_ws, size_t ws_size,
                              hipStream_t stream) {
  const int*   sent  = (const int*)d_in[0];
  const float* embed = (const float*)d_in[1];
  const float* Wih_f = (const float*)d_in[2];
  const float* Whh_f = (const float*)d_in[3];
  const float* bih_f = (const float*)d_in[4];
  const float* bhh_f = (const float*)d_in[5];
  const float* Wih_b = (const float*)d_in[6];
  const float* Whh_b = (const float*)d_in[7];
  const float* bih_b = (const float*)d_in[8];
  const float* bhh_b = (const float*)d_in[9];
  const float* Wout  = (const float*)d_in[10];
  const float* bout  = (const float*)d_in[11];
  const float* trans = (const float*)d_in[12];
  const float* h0    = (const float*)d_in[13];
  const float* c0    = (const float*)d_in[14];
  float* out = (float*)d_out;

  char* ws = (char*)d_ws;
  const size_t xgBytes   = (size_t)Bn * Tn * G4 * sizeof(float);  // 64 MiB
  const size_t featBytes = (size_t)Bn * Tn * Hn * sizeof(float);  // 32 MiB
  const size_t emBytes   = (size_t)Bn * Tn * Kn * sizeof(float);  //  3 MiB
  const int projGrid = (Bn * Tn) / 64;  // 1024

  if (ws_size >= 2 * xgBytes + featBytes + emBytes) {
    float* xgF   = (float*)ws;
    float* xgB   = (float*)(ws + xgBytes);
    float* feats = (float*)(ws + 2 * xgBytes);
    float* emis  = (float*)(ws + 2 * xgBytes + featBytes);
    proj_kernel<<<projGrid, 256, 0, stream>>>(sent, embed, Wih_f, bih_f, bhh_f, xgF);
    proj_kernel<<<projGrid, 256, 0, stream>>>(sent, embed, Wih_b, bih_b, bhh_b, xgB);
    lstm_kernel<<<256, 512, 0, stream>>>(xgF, xgB, Whh_f, Whh_b, h0, c0, feats, -1);
    emis_kernel<<<256, 256, 0, stream>>>(feats, Wout, bout, emis);
    viterbi_kernel<<<128, 64, 0, stream>>>(emis, trans, out);
  } else {
    float* xgS   = (float*)ws;
    float* feats = (float*)(ws + xgBytes);
    float* emis  = (float*)(ws + xgBytes + featBytes);
    proj_kernel<<<projGrid, 256, 0, stream>>>(sent, embed, Wih_f, bih_f, bhh_f, xgS);
    lstm_kernel<<<128, 512, 0, stream>>>(xgS, xgS, Whh_f, Whh_f, h0, c0, feats, 0);
    proj_kernel<<<projGrid, 256, 0, stream>>>(sent, embed, Wih_b, bih_b, bhh_b, xgS);
    lstm_kernel<<<128, 512, 0, stream>>>(xgS, xgS, Whh_b, Whh_b, h0, c0, feats, 1);
    emis_kernel<<<256, 256, 0, stream>>>(feats, Wout, bout, emis);
    viterbi_kernel<<<128, 64, 0, stream>>>(emis, trans, out);
  }
}

// Round 8
// 455.726 us; speedup vs baseline: 1.0603x; 1.0436x over previous
//
#include <hip/hip_runtime.h>
#include <hip/hip_bf16.h>

#define Bn 128
#define Tn 512
#define En 100
#define G4 256   // 4*HD
#define Hn 128
#define Kn 12

// Raw barrier: lgkmcnt(0) ensures in-flight LDS ops landed (cross-wave WAR
// safety), s_barrier without the compiler's vmcnt(0) drain so global
// prefetch loads stay in flight across it.
__device__ __forceinline__ void wg_barrier() {
  asm volatile("s_waitcnt lgkmcnt(0)" ::: "memory");
  __builtin_amdgcn_s_barrier();
  asm volatile("" ::: "memory");
}

__device__ __forceinline__ float exp2_hw(float x) {
  float r; asm("v_exp_f32 %0, %1" : "=v"(r) : "v"(x)); return r;
}
__device__ __forceinline__ float rcp_hw(float x) {
  float r; asm("v_rcp_f32 %0, %1" : "=v"(r) : "v"(x)); return r;
}
__device__ __forceinline__ float fast_tanh(float x) {
  return 1.0f - 2.0f * rcp_hw(1.0f + exp2_hw(x * 2.8853900817779268f));
}

// ---------------- K1: embedding gather + input projection ----------------
__global__ __launch_bounds__(256) void proj_kernel(
    const int* __restrict__ sent, const float* __restrict__ embed,
    const float* __restrict__ Wih, const float* __restrict__ bih,
    const float* __restrict__ bhh, float* __restrict__ xg) {
  __shared__ __align__(16) float embT[En * 64];  // [e][r]
  __shared__ __align__(16) float Wt[En * 64];    // [e][g_local]
  __shared__ __align__(16) float bias_s[64];
  const int tid = threadIdx.x;
  const int n0 = blockIdx.x * 64;
  const int r = tid >> 2;
  const int eo = (tid & 3) * 25;
  {
    const int row = sent[n0 + r];
    const float* erow = embed + (size_t)row * En;
#pragma unroll
    for (int i = 0; i < 25; ++i) embT[(eo + i) * 64 + r] = erow[eo + i];
  }
  const int rg = tid & 15;
  const int gg = tid >> 4;
  for (int ch = 0; ch < 4; ++ch) {
    {
      const float* wrow = Wih + (size_t)(ch * 64 + r) * En;
#pragma unroll
      for (int i = 0; i < 25; ++i) Wt[(eo + i) * 64 + r] = wrow[eo + i];
      if (tid < 64) bias_s[tid] = bih[ch * 64 + tid] + bhh[ch * 64 + tid];
    }
    __syncthreads();
    float acc[4][4];
    {
      const float4 bv = *(const float4*)&bias_s[4 * gg];
#pragma unroll
      for (int i = 0; i < 4; ++i) {
        acc[i][0] = bv.x; acc[i][1] = bv.y; acc[i][2] = bv.z; acc[i][3] = bv.w;
      }
    }
#pragma unroll 4
    for (int e = 0; e < En; ++e) {
      const float4 a = *(const float4*)&embT[e * 64 + 4 * rg];
      const float4 w = *(const float4*)&Wt[e * 64 + 4 * gg];
      acc[0][0] = fmaf(a.x, w.x, acc[0][0]); acc[0][1] = fmaf(a.x, w.y, acc[0][1]);
      acc[0][2] = fmaf(a.x, w.z, acc[0][2]); acc[0][3] = fmaf(a.x, w.w, acc[0][3]);
      acc[1][0] = fmaf(a.y, w.x, acc[1][0]); acc[1][1] = fmaf(a.y, w.y, acc[1][1]);
      acc[1][2] = fmaf(a.y, w.z, acc[1][2]); acc[1][3] = fmaf(a.y, w.w, acc[1][3]);
      acc[2][0] = fmaf(a.z, w.x, acc[2][0]); acc[2][1] = fmaf(a.z, w.y, acc[2][1]);
      acc[2][2] = fmaf(a.z, w.z, acc[2][2]); acc[2][3] = fmaf(a.z, w.w, acc[2][3]);
      acc[3][0] = fmaf(a.w, w.x, acc[3][0]); acc[3][1] = fmaf(a.w, w.y, acc[3][1]);
      acc[3][2] = fmaf(a.w, w.z, acc[3][2]); acc[3][3] = fmaf(a.w, w.w, acc[3][3]);
    }
#pragma unroll
    for (int i = 0; i < 4; ++i) {
      *(float4*)&xg[(size_t)(n0 + 4 * rg + i) * G4 + ch * 64 + 4 * gg] =
          make_float4(acc[i][0], acc[i][1], acc[i][2], acc[i][3]);
    }
    __syncthreads();
  }
}

// ---------------- K2: LSTM recurrence (in-wave gate gather) ----------------
// One block (512 threads) per (dir,b) pair. Wave w owns units 8w..8w+7.
// lane = kh*32 + gt*8 + u : (K-half, gate-type, unit). Per lane: 32-long
// half-dot; weights pinned in AGPRs (r6-proven), batch-read back with
// v_accvgpr_read right after the h ds_reads issue so the 2-cyc reads hide
// under LDS latency instead of sitting on the FMA chain. K-halves combine
// via shfl_xor(32); the 4 gate types of unit u sit at lane^8/^16/^24 ->
// gathered with 3 shuffles, REMOVING the gates LDS round-trip (r6) from the
// serial chain. Only exchange left: h via double-buffered h_s, 1 barrier.
__global__ __launch_bounds__(512, 2) void lstm_kernel(
    const float* __restrict__ xgF, const float* __restrict__ xgB,
    const float* __restrict__ WhhF, const float* __restrict__ WhhB,
    const float* __restrict__ h0, const float* __restrict__ c0,
    float* __restrict__ feats, int dirSel) {
  __shared__ __align__(16) float h_s[2][64];
  int d, b;
  if (dirSel < 0) { d = blockIdx.x >> 7; b = blockIdx.x & 127; }
  else            { d = dirSel;          b = blockIdx.x; }
  const int tid = threadIdx.x;
  const int lane = tid & 63;
  const int w = tid >> 6;          // wave 0..7
  const int kh = lane >> 5;        // K half
  const int gt = (lane >> 3) & 3;  // gate type 0:i 1:f 2:g 3:o
  const int u = lane & 7;
  const int unit = 8 * w + u;
  const int row = gt * 64 + unit;  // W_hh row
  const float* xg = d ? xgB : xgF;
  const float* Whh = d ? WhhB : WhhF;
  // --- load 32 weights once, pin in AGPRs ---
  float a00,a01,a02,a03,a04,a05,a06,a07,a08,a09,a10,a11,a12,a13,a14,a15,
        a16,a17,a18,a19,a20,a21,a22,a23,a24,a25,a26,a27,a28,a29,a30,a31;
  {
    const float4* wp = (const float4*)(Whh + (size_t)row * 64 + 32 * kh);
    const float4 w0 = wp[0], w1 = wp[1], w2 = wp[2], w3 = wp[3];
    const float4 w4 = wp[4], w5 = wp[5], w6 = wp[6], w7 = wp[7];
#define ST(A, V) asm volatile("v_accvgpr_write_b32 %0, %1" : "=a"(A) : "v"(V))
    ST(a00, w0.x); ST(a01, w0.y); ST(a02, w0.z); ST(a03, w0.w);
    ST(a04, w1.x); ST(a05, w1.y); ST(a06, w1.z); ST(a07, w1.w);
    ST(a08, w2.x); ST(a09, w2.y); ST(a10, w2.z); ST(a11, w2.w);
    ST(a12, w3.x); ST(a13, w3.y); ST(a14, w3.z); ST(a15, w3.w);
    ST(a16, w4.x); ST(a17, w4.y); ST(a18, w4.z); ST(a19, w4.w);
    ST(a20, w5.x); ST(a21, w5.y); ST(a22, w5.z); ST(a23, w5.w);
    ST(a24, w6.x); ST(a25, w6.y); ST(a26, w6.z); ST(a27, w6.w);
    ST(a28, w7.x); ST(a29, w7.y); ST(a30, w7.z); ST(a31, w7.w);
#undef ST
  }
  // activation constants per lane: act = A + B * rcp(1 + exp2(C*x))
  const bool isT = (gt == 2);
  const float fA = isT ? 1.0f : 0.0f;
  const float fB = isT ? -2.0f : 1.0f;
  const float fC = isT ? 2.8853900817779268f : -1.4426950408889634f;
  float c = 0.f;
  if (lane < 8) {  // gt==0 && kh==0: unit owner
    c = c0[(size_t)d * (Bn * 64) + (size_t)b * 64 + unit];
    h_s[0][unit] = h0[(size_t)d * (Bn * 64) + (size_t)b * 64 + unit];
  }
  const float* xb = xg + (size_t)b * Tn * G4 + row;
  float* fbase = feats + (size_t)b * Tn * Hn + d * 64 + unit;
  const int t0 = d ? (Tn - 1) : 0;
  const int ts = d ? -1 : 1;
  float p0 = 0.f, p1 = 0.f, p2 = 0.f, p3 = 0.f;
  if (kh == 0) {
    p0 = xb[(size_t)t0 * G4];
    p1 = xb[(size_t)(t0 + ts) * G4];
    p2 = xb[(size_t)(t0 + 2 * ts) * G4];
    p3 = xb[(size_t)(t0 + 3 * ts) * G4];
  }

#define ARD(U, A) asm volatile("v_accvgpr_read_b32 %0, %1" : "=v"(U) : "a"(A))
#define F4(S0, S1, S2, S3, HV, U0, U1, U2, U3)                                 \
    S0 = fmaf((HV).x, U0, S0); S1 = fmaf((HV).y, U1, S1);                      \
    S2 = fmaf((HV).z, U2, S2); S3 = fmaf((HV).w, U3, S3);

#define LSTM_STEP(P, TT, RB) do {                                              \
    wg_barrier();                                                              \
    const float4* hp = (const float4*)(&h_s[RB][32 * kh]);                     \
    const float4 h0v = hp[0], h1v = hp[1], h2v = hp[2], h3v = hp[3];           \
    const float4 h4v = hp[4], h5v = hp[5], h6v = hp[6], h7v = hp[7];           \
    float u00,u01,u02,u03,u04,u05,u06,u07,u08,u09,u10,u11,u12,u13,u14,u15,     \
          u16,u17,u18,u19,u20,u21,u22,u23,u24,u25,u26,u27,u28,u29,u30,u31;     \
    ARD(u00,a00); ARD(u01,a01); ARD(u02,a02); ARD(u03,a03);                    \
    ARD(u04,a04); ARD(u05,a05); ARD(u06,a06); ARD(u07,a07);                    \
    ARD(u08,a08); ARD(u09,a09); ARD(u10,a10); ARD(u11,a11);                    \
    ARD(u12,a12); ARD(u13,a13); ARD(u14,a14); ARD(u15,a15);                    \
    ARD(u16,a16); ARD(u17,a17); ARD(u18,a18); ARD(u19,a19);                    \
    ARD(u20,a20); ARD(u21,a21); ARD(u22,a22); ARD(u23,a23);                    \
    ARD(u24,a24); ARD(u25,a25); ARD(u26,a26); ARD(u27,a27);                    \
    ARD(u28,a28); ARD(u29,a29); ARD(u30,a30); ARD(u31,a31);                    \
    float s0 = 0.f, s1 = 0.f, s2 = 0.f, s3 = 0.f;                              \
    F4(s0,s1,s2,s3, h0v, u00,u01,u02,u03)                                      \
    F4(s0,s1,s2,s3, h1v, u04,u05,u06,u07)                                      \
    F4(s0,s1,s2,s3, h2v, u08,u09,u10,u11)                                      \
    F4(s0,s1,s2,s3, h3v, u12,u13,u14,u15)                                      \
    F4(s0,s1,s2,s3, h4v, u16,u17,u18,u19)                                      \
    F4(s0,s1,s2,s3, h5v, u20,u21,u22,u23)                                      \
    F4(s0,s1,s2,s3, h6v, u24,u25,u26,u27)                                      \
    F4(s0,s1,s2,s3, h7v, u28,u29,u30,u31)                                      \
    const float smine = (s0 + s1) + (s2 + s3);                                 \
    const float stot = smine + __shfl_xor(smine, 32);                          \
    const float accv = (P) + stot;                                             \
    const float act = fmaf(fB, rcp_hw(1.0f + exp2_hw(fC * accv)), fA);         \
    const float gF = __shfl_xor(act, 8);                                       \
    const float gG = __shfl_xor(act, 16);                                      \
    const float gO = __shfl_xor(act, 24);                                      \
    if (lane < 8) {                                                            \
      c = fmaf(gF, c, act * gG);                                               \
      const float hh = gO * fast_tanh(c);                                      \
      h_s[RB ^ 1][unit] = hh;                                                  \
      fbase[(size_t)(TT) * Hn] = hh;                                           \
    }                                                                          \
  } while (0)

  for (int s = 0; s < Tn; s += 4) {
    const int tA = t0 + s * ts;
    LSTM_STEP(p0, tA, 0);
    if (kh == 0 && s + 4 < Tn) p0 = xb[(size_t)(t0 + (s + 4) * ts) * G4];
    LSTM_STEP(p1, tA + ts, 1);
    if (kh == 0 && s + 5 < Tn) p1 = xb[(size_t)(t0 + (s + 5) * ts) * G4];
    LSTM_STEP(p2, tA + 2 * ts, 0);
    if (kh == 0 && s + 6 < Tn) p2 = xb[(size_t)(t0 + (s + 6) * ts) * G4];
    LSTM_STEP(p3, tA + 3 * ts, 1);
    if (kh == 0 && s + 7 < Tn) p3 = xb[(size_t)(t0 + (s + 7) * ts) * G4];
  }
#undef LSTM_STEP
#undef F4
#undef ARD
}

// ---------------- K3: emissions = feats @ W_out^T + b_out ----------------
__global__ __launch_bounds__(256) void emis_kernel(
    const float* __restrict__ feats, const float* __restrict__ Wout,
    const float* __restrict__ bout, float* __restrict__ em) {
  __shared__ __align__(16) float Wo[Kn * Hn];
  __shared__ float bo[Kn];
  const int tid = threadIdx.x;
  for (int i = tid; i < Kn * Hn; i += 256) Wo[i] = Wout[i];
  if (tid < Kn) bo[tid] = bout[tid];
  __syncthreads();
  const int n = blockIdx.x * 256 + tid;
  float acc[Kn];
#pragma unroll
  for (int k = 0; k < Kn; ++k) acc[k] = bo[k];
  const float4* fp = (const float4*)(feats + (size_t)n * Hn);
#pragma unroll 4
  for (int d4 = 0; d4 < 32; ++d4) {
    const float4 v = fp[d4];
#pragma unroll
    for (int k = 0; k < Kn; ++k) {
      const float4 w = *(const float4*)&Wo[k * Hn + d4 * 4];
      acc[k] = fmaf(v.x, w.x, acc[k]);
      acc[k] = fmaf(v.y, w.y, acc[k]);
      acc[k] = fmaf(v.z, w.z, acc[k]);
      acc[k] = fmaf(v.w, w.w, acc[k]);
    }
  }
  float* ep = em + (size_t)n * Kn;
#pragma unroll
  for (int k = 0; k < Kn; k += 4)
    *(float4*)&ep[k] = make_float4(acc[k], acc[k + 1], acc[k + 2], acc[k + 3]);
}

// ---------------- K4: Viterbi (one wave per sentence) ----------------
#define AMAX(v, a, v2, a2) { if ((v2) > (v)) { (v) = (v2); (a) = (a2); } }

__global__ __launch_bounds__(64) void viterbi_kernel(
    const float* __restrict__ em, const float* __restrict__ trans,
    float* __restrict__ out) {
  __shared__ __align__(16) float em_s[Tn * Kn];
  __shared__ float trans_s[Kn * Kn];
  __shared__ unsigned char bp[(Tn - 1) * Kn];
  __shared__ short path_s[Tn];
  const int tid = threadIdx.x;
  const int b = blockIdx.x;
  {
    const float4* ebv = (const float4*)(em + (size_t)b * Tn * Kn);
    float4* emv = (float4*)em_s;
    for (int i = tid; i < (Tn * Kn) / 4; i += 64) emv[i] = ebv[i];
  }
  for (int i = tid; i < Kn * Kn; i += 64) trans_s[i] = trans[i];
  __syncthreads();
  const int lane = (tid < Kn) ? tid : 0;  // lane = to-tag
  float treg[Kn];
#pragma unroll
  for (int f = 0; f < Kn; ++f) treg[f] = trans_s[f * Kn + lane];
  float prev = em_s[lane];
  for (int t = 1; t < Tn; ++t) {
    float cv[Kn];
#pragma unroll
    for (int f = 0; f < Kn; ++f) cv[f] = __shfl(prev, f) + treg[f];
    float m0 = cv[0], m1 = cv[2], m2 = cv[4], m3 = cv[6], m4 = cv[8], m5 = cv[10];
    int a0 = 0, a1 = 2, a2 = 4, a3 = 6, a4 = 8, a5 = 10;
    AMAX(m0, a0, cv[1], 1);  AMAX(m1, a1, cv[3], 3);
    AMAX(m2, a2, cv[5], 5);  AMAX(m3, a3, cv[7], 7);
    AMAX(m4, a4, cv[9], 9);  AMAX(m5, a5, cv[11], 11);
    AMAX(m0, a0, m1, a1); AMAX(m2, a2, m3, a3); AMAX(m4, a4, m5, a5);
    AMAX(m0, a0, m2, a2); AMAX(m0, a0, m4, a4);
    prev = em_s[t * Kn + lane] + m0;
    if (tid < Kn) bp[(t - 1) * Kn + tid] = (unsigned char)a0;
  }
  float fv[Kn];
#pragma unroll
  for (int f = 0; f < Kn; ++f) fv[f] = __shfl(prev, f);
  float m0 = fv[0], m1 = fv[2], m2 = fv[4], m3 = fv[6], m4 = fv[8], m5 = fv[10];
  int a0 = 0, a1 = 2, a2 = 4, a3 = 6, a4 = 8, a5 = 10;
  AMAX(m0, a0, fv[1], 1);  AMAX(m1, a1, fv[3], 3);
  AMAX(m2, a2, fv[5], 5);  AMAX(m3, a3, fv[7], 7);
  AMAX(m4, a4, fv[9], 9);  AMAX(m5, a5, fv[11], 11);
  AMAX(m0, a0, m1, a1); AMAX(m2, a2, m3, a3); AMAX(m4, a4, m5, a5);
  AMAX(m0, a0, m2, a2); AMAX(m0, a0, m4, a4);
  __syncthreads();
  if (tid == 0) {
    out[b] = m0;
    int cur = a0;
    for (int i = Tn - 2; i >= 0; --i) {
      path_s[i + 1] = (short)cur;
      cur = bp[i * Kn + cur];
    }
    path_s[0] = (short)cur;
  }
  __syncthreads();
  for (int i = tid; i < Tn; i += 64)
    out[Bn + (size_t)b * Tn + i] = (float)path_s[i];
}

extern "C" void kernel_launch(void* const* d_in, const int* in_sizes, int n_in,
                              void* d_out, int out_size, void* d_ws, size_t ws_size,
                              hipStream_t stream) {
  const int*   sent  = (const int*)d_in[0];
  const float* embed = (const float*)d_in[1];
  const float* Wih_f = (const float*)d_in[2];
  const float* Whh_f = (const float*)d_in[3];
  const float* bih_f = (const float*)d_in[4];
  const float* bhh_f = (const float*)d_in[5];
  const float* Wih_b = (const float*)d_in[6];
  const float* Whh_b = (const float*)d_in[7];
  const float* bih_b = (const float*)d_in[8];
  const float* bhh_b = (const float*)d_in[9];
  const float* Wout  = (const float*)d_in[10];
  const float* bout  = (const float*)d_in[11];
  const float* trans = (const float*)d_in[12];
  const float* h0    = (const float*)d_in[13];
  const float* c0    = (const float*)d_in[14];
  float* out = (float*)d_out;

  char* ws = (char*)d_ws;
  const size_t xgBytes   = (size_t)Bn * Tn * G4 * sizeof(float);  // 64 MiB
  const size_t featBytes = (size_t)Bn * Tn * Hn * sizeof(float);  // 32 MiB
  const size_t emBytes   = (size_t)Bn * Tn * Kn * sizeof(float);  //  3 MiB
  const int projGrid = (Bn * Tn) / 64;  // 1024

  if (ws_size >= 2 * xgBytes + featBytes + emBytes) {
    float* xgF   = (float*)ws;
    float* xgB   = (float*)(ws + xgBytes);
    float* feats = (float*)(ws + 2 * xgBytes);
    float* emis  = (float*)(ws + 2 * xgBytes + featBytes);
    proj_kernel<<<projGrid, 256, 0, stream>>>(sent, embed, Wih_f, bih_f, bhh_f, xgF);
    proj_kernel<<<projGrid, 256, 0, stream>>>(sent, embed, Wih_b, bih_b, bhh_b, xgB);
    lstm_kernel<<<256, 512, 0, stream>>>(xgF, xgB, Whh_f, Whh_b, h0, c0, feats, -1);
    emis_kernel<<<256, 256, 0, stream>>>(feats, Wout, bout, emis);
    viterbi_kernel<<<128, 64, 0, stream>>>(emis, trans, out);
  } else {
    float* xgS   = (float*)ws;
    float* feats = (float*)(ws + xgBytes);
    float* emis  = (float*)(ws + xgBytes + featBytes);
    proj_kernel<<<projGrid, 256, 0, stream>>>(sent, embed, Wih_f, bih_f, bhh_f, xgS);
    lstm_kernel<<<128, 512, 0, stream>>>(xgS, xgS, Whh_f, Whh_f, h0, c0, feats, 0);
    proj_kernel<<<projGrid, 256, 0, stream>>>(sent, embed, Wih_b, bih_b, bhh_b, xgS);
    lstm_kernel<<<128, 512, 0, stream>>>(xgS, xgS, Whh_b, Whh_b, h0, c0, feats, 1);
    emis_kernel<<<256, 256, 0, stream>>>(feats, Wout, bout, emis);
    viterbi_kernel<<<128, 64, 0, stream>>>(emis, trans, out);
  }
}